// Round 3
// baseline (468.126 us; speedup 1.0000x reference)
//
#include <hip/hip_runtime.h>
#include <hip/hip_bf16.h>
#include <hip/hip_fp16.h>
#include <math.h>

// SGC: out = log_softmax( S^2 X W^T + b ), S = D^-1/2 (A+I) D^-1/2
// t = dis .* (X W^T) in f16, split: tA = classes 0..31 (64 B rows),
// tB = classes 32..39 (16 B rows).
// KEY (round 3): each dst's edge list is SORTED BY SRC (per-thread insertion
// sort in p4's LDS). All ~8K waves progress in near-lockstep, so the whole
// machine sweeps the table as a ~2 MB sliding window that fits per-XCD L2.
// This attacks the measured invariant dur ~= L2-miss bytes / 3 TB/s by
// collapsing the miss rate instead of re-packing rows.
// Propagation: one 5-lane GROUP per dst node (12 nodes/wave). Lanes 0-3 own
// 16 B of the A row; lane 4 owns the B row. f32 accumulation, no folds.
// CSR via two-level bucketed counting sort with power-of-2 bucket ranges.

#define N_NODES 100000
#define N_FEAT  128
#define N_CLASS 40

#define RANGE   256           // dsts per fine bucket (pow2: dst>>8)
#define NBALLOC 512
#define NBUSED  391           // ceil(100000/256)
#define RANGE_C 2048          // dsts per coarse bucket (dst>>11)
#define NCALLOC 64
#define NCUSED  49            // ceil(100000/2048)
#define CAP     8704          // fine bucket LDS cap (mean 8192 + ~5.7 sigma)
#define CCAP    67072         // coarse region cap (mean 65536 + ~6 sigma)
#define P3AGRID 1024

typedef __attribute__((ext_vector_type(8))) short short8;   // 8 bf16 (4 VGPRs)
typedef __attribute__((ext_vector_type(4))) float floatx4;  // MFMA C/D
typedef __attribute__((ext_vector_type(4))) int intx4;      // nt-load vector

// ---------------------------------------------------------------------------
// Detect int32 vs int64 edge_index words; zero counters. 1 block x 512.
__global__ void detect_zero_kernel(const int* __restrict__ ei, int* __restrict__ flag,
                                   int* __restrict__ bucketCount,
                                   int* __restrict__ coarseCnt) {
    int t = threadIdx.x;
    if (t < NBALLOC) bucketCount[t] = 0;
    if (t < NCALLOC) coarseCnt[t] = 0;
    if (t < 64) {
        int nz = (ei[2 * t + 1] != 0) ? 1 : 0;
        unsigned long long b = __ballot(nz);
        if (t == 0) *flag = (b == 0ull) ? 1 : 0;   // 1 => int64 layout
    }
}

__device__ __forceinline__ int edge_word(const int* ei, int elem, int is64) {
    return is64 ? ei[2 * elem] : ei[elem];
}

// P3a: scatter packed records (dstLocalCoarse<<17 | src) into per-block dense
// runs within coarse regions; simultaneously build the fine histogram.
__global__ __launch_bounds__(256) void p3a_scatter(
    const int* __restrict__ ei, int E, const int* __restrict__ flag,
    int* __restrict__ bucketCount, int* __restrict__ coarseCnt,
    unsigned int* __restrict__ tmpc)
{
    __shared__ int hf[NBALLOC];
    __shared__ int hc[NCALLOC];
    __shared__ int basec[NCALLOC];
    __shared__ int curc[NCALLOC];
    int t = threadIdx.x;
    for (int i = t; i < NBALLOC; i += 256) hf[i] = 0;
    if (t < NCALLOC) hc[t] = 0;
    __syncthreads();
    int is64 = *flag;
    int per = (E + gridDim.x - 1) / gridDim.x;
    int e0 = blockIdx.x * per;
    int e1 = min(E, e0 + per);
    for (int e = e0 + t; e < e1; e += 256) {
        int c = edge_word(ei, E + e, is64);
        atomicAdd(&hf[c >> 8], 1);
        atomicAdd(&hc[c >> 11], 1);
    }
    __syncthreads();
    if (t < NCALLOC) {
        basec[t] = hc[t] ? atomicAdd(&coarseCnt[t], hc[t]) : 0;
        curc[t] = 0;
    }
    for (int i = t; i < NBALLOC; i += 256)
        if (hf[i]) atomicAdd(&bucketCount[i], hf[i]);
    __syncthreads();
    for (int e = e0 + t; e < e1; e += 256) {
        int c = edge_word(ei, E + e, is64);
        int r = edge_word(ei, e, is64);
        int cb = c >> 11;
        int p = basec[cb] + atomicAdd(&curc[cb], 1);
        if (p < CCAP)
            tmpc[(size_t)cb * CCAP + p] = ((unsigned)(c & 2047) << 17) | (unsigned)r;
    }
}

// P2: scan fine counts -> bucketStart/bucketCursor; starts[N]=E.
__global__ __launch_bounds__(NBALLOC) void p2_scan(
    const int* __restrict__ bucketCount, int* __restrict__ bucketStart,
    int* __restrict__ bucketCursor, int* __restrict__ starts, int E)
{
    __shared__ int s[NBALLOC];
    int t = threadIdx.x;
    int v = bucketCount[t];
    s[t] = v;
    __syncthreads();
    for (int o = 1; o < NBALLOC; o <<= 1) {
        int y = (t >= o) ? s[t - o] : 0;
        __syncthreads();
        s[t] += y;
        __syncthreads();
    }
    int incl = s[t], excl = incl - v;
    bucketStart[t] = excl;
    bucketCursor[t] = excl;
    if (t == NBALLOC - 1) { bucketStart[NBALLOC] = incl; starts[N_NODES] = E; }
}

// P3b: 8 blocks per coarse bucket; re-scatter into its 8 fine buckets.
__global__ __launch_bounds__(256) void p3b_scatter(
    const unsigned int* __restrict__ tmpc, const int* __restrict__ coarseCnt,
    int* __restrict__ bucketCursor, unsigned int* __restrict__ tmp)
{
    __shared__ int fh[8];
    __shared__ int fb[8];
    __shared__ int fc[8];
    int cb = blockIdx.x >> 3;
    int j = blockIdx.x & 7;
    int t = threadIdx.x;
    int cnt = coarseCnt[cb];
    if (cnt > CCAP) cnt = CCAP;
    int chunk = (cnt + 7) >> 3;
    int r0 = j * chunk;
    int r1 = min(cnt, r0 + chunk);
    if (t < 8) fh[t] = 0;
    __syncthreads();
    const unsigned int* rec = tmpc + (size_t)cb * CCAP;
    for (int i = r0 + t; i < r1; i += 256) {
        int dlc = (int)(rec[i] >> 17);
        atomicAdd(&fh[dlc >> 8], 1);
    }
    __syncthreads();
    if (t < 8) {
        fb[t] = fh[t] ? atomicAdd(&bucketCursor[cb * 8 + t], fh[t]) : 0;
        fc[t] = 0;
    }
    __syncthreads();
    for (int i = r0 + t; i < r1; i += 256) {
        unsigned v = rec[i];
        int dlc = (int)(v >> 17);
        unsigned src = v & 0x1FFFFu;
        int fi = dlc >> 8;
        int dlf = dlc & 255;
        int p = fb[fi] + atomicAdd(&fc[fi], 1);
        tmp[p] = ((unsigned)dlf << 24) | src;
    }
}

// P4: per-fine-bucket LDS counting sort -> starts, dis, srcsB (RAW src ids,
// coalesced), then per-dst insertion sort BY SRC in LDS (one thread per dst)
// so hop kernels sweep the gather table as a sliding window.
__global__ __launch_bounds__(256) void p4_sort(
    const unsigned int* __restrict__ tmp, const int* __restrict__ bucketStart,
    int* __restrict__ starts, float* __restrict__ dis, int* __restrict__ srcsB, int N)
{
    __shared__ int srt[CAP];
    __shared__ int hist[256];
    __shared__ int sc[256];
    __shared__ int cur[256];
    int b = blockIdx.x, t = threadIdx.x;
    int g0 = b * RANGE;
    int gcnt = N - g0;
    if (gcnt > RANGE) gcnt = RANGE;
    int base = bucketStart[b];
    int n = bucketStart[b + 1] - base;
    hist[t] = 0;
    __syncthreads();
    for (int i = t; i < n; i += 256)
        atomicAdd(&hist[tmp[base + i] >> 24], 1);
    __syncthreads();
    int hv = hist[t];
    sc[t] = hv;
    __syncthreads();
    for (int o = 1; o < 256; o <<= 1) {
        int y = (t >= o) ? sc[t - o] : 0;
        __syncthreads();
        sc[t] += y;
        __syncthreads();
    }
    int excl = sc[t] - hv;
    if (t < gcnt) {
        starts[g0 + t] = base + excl;
        dis[g0 + t] = rsqrtf((float)(hv + 1));   // +1 self-loop
    }
    cur[t] = excl;
    __syncthreads();
    if (n <= CAP) {
        for (int i = t; i < n; i += 256) {
            unsigned v = tmp[base + i];
            int p = atomicAdd(&cur[v >> 24], 1);
            srt[p] = (int)(v & 0xFFFFFFu);        // raw src id
        }
        __syncthreads();
        // per-dst insertion sort by src: thread t owns segment [excl, excl+hv)
        {
            int lo = excl, hi = excl + hv;
            for (int i = lo + 1; i < hi; ++i) {
                int v = srt[i];
                int j = i - 1;
                while (j >= lo && srt[j] > v) { srt[j + 1] = srt[j]; --j; }
                srt[j + 1] = v;
            }
        }
        __syncthreads();
        for (int i = t; i < n; i += 256) srcsB[base + i] = srt[i];
    } else {
        // overflow fallback (statistically never taken; unsorted is correct)
        for (int i = t; i < n; i += 256) {
            unsigned v = tmp[base + i];
            int p = atomicAdd(&cur[v >> 24], 1);
            srcsB[base + p] = (int)(v & 0xFFFFFFu);
        }
    }
}

// ---------------------------------------------------------------------------
__device__ __forceinline__ unsigned short f2bf(float f) {   // RTN f32 -> bf16
    unsigned u = __float_as_uint(f);
    unsigned r = u + 0x7FFFu + ((u >> 16) & 1u);
    return (unsigned short)(r >> 16);
}
__device__ __forceinline__ __half2 u2h(unsigned w) {
    union { unsigned u; __half2 h; } c; c.u = w; return c.h;
}
__device__ __forceinline__ unsigned h2u(__half2 h) {
    union { unsigned u; __half2 h; } c; c.h = h; return c.u;
}

// t = dis .* (X @ W^T), f16, split-stored: tA = classes 0..31 (row stride
// 64 B), tB = classes 32..39 (row stride 16 B). One wave per 16 nodes.
__global__ __launch_bounds__(256) void transform_mfma(
    const float* __restrict__ x, const float* __restrict__ W,
    const float* __restrict__ dis, unsigned short* __restrict__ tA,
    unsigned short* __restrict__ tB, int N)
{
    __shared__ uint4 Wl[3 * 4 * 64];        // B frags, bf16-packed: 12 KiB
    int t = threadIdx.x;
    for (int i = t; i < 3 * 4 * 64; i += 256) {
        int lane = i & 63;
        int kc = (i >> 6) & 3;
        int nt = i >> 8;
        int n = nt * 16 + (lane & 15);
        int k = kc * 32 + (lane >> 4) * 8;
        union { unsigned short s[8]; uint4 v; } u;
        #pragma unroll
        for (int j = 0; j < 8; ++j)
            u.s[j] = (n < N_CLASS) ? f2bf(W[n * N_FEAT + k + j]) : (unsigned short)0;
        Wl[i] = u.v;
    }
    __syncthreads();
    int wave = (blockIdx.x * blockDim.x + threadIdx.x) >> 6;
    int lane = threadIdx.x & 63;
    int ntile = (N + 15) / 16;
    if (wave >= ntile) return;
    int m = lane & 15, quad = lane >> 4;
    int row = wave * 16 + m;
    const short8* Wf = reinterpret_cast<const short8*>(Wl);
    floatx4 acc0 = {0.f, 0.f, 0.f, 0.f}, acc1 = acc0, acc2 = acc0;
    #pragma unroll
    for (int kc = 0; kc < 4; ++kc) {
        const float4* xr = reinterpret_cast<const float4*>(
            x + (size_t)row * N_FEAT + kc * 32 + quad * 8);
        float4 a0 = xr[0], a1 = xr[1];
        short8 af;
        af[0] = f2bf(a0.x); af[1] = f2bf(a0.y); af[2] = f2bf(a0.z); af[3] = f2bf(a0.w);
        af[4] = f2bf(a1.x); af[5] = f2bf(a1.y); af[6] = f2bf(a1.z); af[7] = f2bf(a1.w);
        short8 b0 = Wf[(0 * 4 + kc) * 64 + lane];
        short8 b1 = Wf[(1 * 4 + kc) * 64 + lane];
        short8 b2 = Wf[(2 * 4 + kc) * 64 + lane];
        acc0 = __builtin_amdgcn_mfma_f32_16x16x32_bf16(af, b0, acc0, 0, 0, 0);
        acc1 = __builtin_amdgcn_mfma_f32_16x16x32_bf16(af, b1, acc1, 0, 0, 0);
        acc2 = __builtin_amdgcn_mfma_f32_16x16x32_bf16(af, b2, acc2, 0, 0, 0);
    }
    #pragma unroll
    for (int r = 0; r < 4; ++r) {
        int rw = wave * 16 + quad * 4 + r;
        float ds = dis[rw];
        unsigned short* ta = tA + (size_t)rw * 32;
        ta[m] = __half_as_ushort(__float2half(ds * acc0[r]));
        ta[16 + m] = __half_as_ushort(__float2half(ds * acc1[r]));
        if (m < 8) tB[(size_t)rw * 8 + m] = __half_as_ushort(__float2half(ds * acc2[r]));
    }
}

// ---------------------------------------------------------------------------
// Group-per-node gather: 12 groups x 5 lanes per wave. Lanes 0-3 read 16 B
// of the 64 B A-row; lane 4 reads the 16 B B-row. f32 accumulation in two
// banks (A: even edges, B: odd). Edge lists are src-sorted (L2 locality).
struct F8 { float v0, v1, v2, v3, v4, v5, v6, v7; };

__device__ __forceinline__ void acc8(F8& a, uint4 r) {
    float2 f0 = __half22float2(u2h(r.x));
    float2 f1 = __half22float2(u2h(r.y));
    float2 f2 = __half22float2(u2h(r.z));
    float2 f3 = __half22float2(u2h(r.w));
    a.v0 += f0.x; a.v1 += f0.y; a.v2 += f1.x; a.v3 += f1.y;
    a.v4 += f2.x; a.v5 += f2.y; a.v6 += f3.x; a.v7 += f3.y;
}

// Shared gather: group g = lane/5 handles dst d = wave*12+g. Main loop
// unrolled x4 with a nontemporal int4 srcsB load (streamed once: keep it
// out of L2 so gather lines survive). Ghost lanes 60-63 shadow group 11.
#define GATHER5(tAin, tBin)                                                    \
    int wv = (blockIdx.x * blockDim.x + threadIdx.x) >> 6;                     \
    int lane = threadIdx.x & 63;                                               \
    int g = lane / 5;                                                          \
    int sl = lane - g * 5;                                                     \
    if (g > 11) { g = 11; sl = 0; }                                            \
    int d = wv * 12 + g;                                                       \
    int act = (lane < 60) && (d < N);                                          \
    int dc = min(d, N - 1);                                                    \
    int e0 = starts[dc];                                                       \
    int e1 = starts[dc + 1];                                                   \
    if (d >= N) e1 = e0;                                                       \
    int slo = sl << 4;                                                         \
    int isB = (sl == 4);                                                       \
    const char* tbs = isB ? (const char*)(tBin)                                \
                          : ((const char*)(tAin) + slo);                       \
    int shf = isB ? 4 : 6;                                                     \
    F8 A = {0,0,0,0,0,0,0,0}, B = {0,0,0,0,0,0,0,0};                           \
    {                                                                          \
        uint4 rs = *reinterpret_cast<const uint4*>(tbs + ((size_t)dc << shf)); \
        acc8(A, rs);                            /* self term row d */          \
    }                                                                          \
    int e = e0;                                                                \
    int ea = min(e1, (e0 + 3) & ~3);                                           \
    for (; e < ea; ++e) {                       /* align to 16 B */            \
        unsigned o = (unsigned)srcsB[e] << shf;                                \
        uint4 r = *reinterpret_cast<const uint4*>(tbs + o);                    \
        acc8(A, r);                                                            \
    }                                                                          \
    for (; e + 4 <= e1; e += 4) {               /* 4 gathers in flight */      \
        intx4 o4 = __builtin_nontemporal_load(                                 \
            reinterpret_cast<const intx4*>(srcsB + e));                        \
        uint4 r0 = *reinterpret_cast<const uint4*>(tbs + ((unsigned)o4.x << shf)); \
        uint4 r1 = *reinterpret_cast<const uint4*>(tbs + ((unsigned)o4.y << shf)); \
        uint4 r2 = *reinterpret_cast<const uint4*>(tbs + ((unsigned)o4.z << shf)); \
        uint4 r3 = *reinterpret_cast<const uint4*>(tbs + ((unsigned)o4.w << shf)); \
        acc8(A, r0); acc8(B, r1); acc8(A, r2); acc8(B, r3);                    \
    }                                                                          \
    for (; e < e1; ++e) {                       /* tail <= 3 edges */          \
        unsigned o = (unsigned)srcsB[e] << shf;                                \
        uint4 r = *reinterpret_cast<const uint4*>(tbs + o);                    \
        acc8(A, r);                                                            \
    }                                                                          \
    A.v0 += B.v0; A.v1 += B.v1; A.v2 += B.v2; A.v3 += B.v3;                    \
    A.v4 += B.v4; A.v5 += B.v5; A.v6 += B.v6; A.v7 += B.v7;

// Middle hop: tout[d] = f16( dd^2 * (t[d] + sum t[src]) ), split-stored.
__global__ __launch_bounds__(256) void prop_hop_kernel(
    const unsigned short* __restrict__ tAin, const unsigned short* __restrict__ tBin,
    unsigned short* __restrict__ tAout, unsigned short* __restrict__ tBout,
    const int* __restrict__ starts, const int* __restrict__ srcsB,
    const float* __restrict__ dis, int N)
{
    GATHER5(tAin, tBin)
    if (act) {
        float dd = dis[dc];
        float sc = dd * dd;
        uint4 o;
        o.x = h2u(__floats2half2_rn(sc * A.v0, sc * A.v1));
        o.y = h2u(__floats2half2_rn(sc * A.v2, sc * A.v3));
        o.z = h2u(__floats2half2_rn(sc * A.v4, sc * A.v5));
        o.w = h2u(__floats2half2_rn(sc * A.v6, sc * A.v7));
        char* op = isB ? ((char*)tBout + ((size_t)d << 4))
                       : ((char*)tAout + ((size_t)d << 6) + slo);
        *reinterpret_cast<uint4*>(op) = o;
    }
}

// Final hop fused with bias + log_softmax. Softmax reduce = 4 rotate-shfls
// within the 5-lane group (serves all 12 nodes of the wave at once).
__global__ __launch_bounds__(256) void prop_final_kernel(
    const unsigned short* __restrict__ tAin, const unsigned short* __restrict__ tBin,
    float* __restrict__ out,
    const int* __restrict__ starts, const int* __restrict__ srcsB,
    const float* __restrict__ dis, const float* __restrict__ bias, int N)
{
    GATHER5(tAin, tBin)
    float dd = dis[dc];
    float4 blo = reinterpret_cast<const float4*>(bias)[sl * 2];       // sl<5
    float4 bhi = reinterpret_cast<const float4*>(bias)[sl * 2 + 1];
    float v0 = dd * A.v0 + blo.x, v1 = dd * A.v1 + blo.y;
    float v2 = dd * A.v2 + blo.z, v3 = dd * A.v3 + blo.w;
    float v4 = dd * A.v4 + bhi.x, v5 = dd * A.v5 + bhi.y;
    float v6 = dd * A.v6 + bhi.z, v7 = dd * A.v7 + bhi.w;
    float mx = fmaxf(fmaxf(fmaxf(v0, v1), fmaxf(v2, v3)),
                     fmaxf(fmaxf(v4, v5), fmaxf(v6, v7)));
    int rot = g * 5 + ((sl + 1 == 5) ? 0 : sl + 1);     // next lane in group
    float tmx = mx;
    #pragma unroll
    for (int k = 0; k < 4; ++k) { tmx = __shfl(tmx, rot); mx = fmaxf(mx, tmx); }
    float s = expf(v0 - mx) + expf(v1 - mx) + expf(v2 - mx) + expf(v3 - mx)
            + expf(v4 - mx) + expf(v5 - mx) + expf(v6 - mx) + expf(v7 - mx);
    float ts = s;
    #pragma unroll
    for (int k = 0; k < 4; ++k) { ts = __shfl(ts, rot); s += ts; }
    if (act) {
        float ls = mx + logf(s);
        float* ro = out + (size_t)d * N_CLASS + sl * 8;
        floatx4 lo = {v0 - ls, v1 - ls, v2 - ls, v3 - ls};
        floatx4 hi = {v4 - ls, v5 - ls, v6 - ls, v7 - ls};
        __builtin_nontemporal_store(lo, reinterpret_cast<floatx4*>(ro));
        __builtin_nontemporal_store(hi, reinterpret_cast<floatx4*>(ro) + 1);
    }
}

// ---------------------------------------------------------------------------
extern "C" void kernel_launch(void* const* d_in, const int* in_sizes, int n_in,
                              void* d_out, int out_size, void* d_ws, size_t ws_size,
                              hipStream_t stream) {
    const float* feature = (const float*)d_in[0];   // [N, 128]
    const float* weight  = (const float*)d_in[1];   // [40, 128]
    const float* bias    = (const float*)d_in[2];   // [40]
    const int*   ei      = (const int*)d_in[3];     // [2, E] (int32 or int64 words)
    const int N = N_NODES;
    const int E = in_sizes[3] / 2;

    size_t off = 0;
    auto take = [&](size_t bytes) { size_t o = off; off += (bytes + 255) & ~(size_t)255; return o; };
    char* ws = (char*)d_ws;
    int*   flag      = (int*)  (ws + take(4));
    int*   bCount    = (int*)  (ws + take((size_t)NBALLOC * 4));
    int*   bStart    = (int*)  (ws + take((size_t)(NBALLOC + 1) * 4));
    int*   bCursor   = (int*)  (ws + take((size_t)NBALLOC * 4));
    int*   coarseCnt = (int*)  (ws + take((size_t)NCALLOC * 4));
    int*   starts    = (int*)  (ws + take((size_t)(N + 1) * 4));
    float* dis       = (float*)(ws + take((size_t)N * 4));
    // srcsB region also hosts tmpc (coarse records): tmpc dead before p4 writes srcsB
    size_t srcsBytes = (size_t)E * 4;
    size_t tmpcBytes = (size_t)NCALLOC * CCAP * 4;
    size_t bigBytes = srcsBytes > tmpcBytes ? srcsBytes : tmpcBytes;
    char* bigBase = ws + take(bigBytes);
    int* srcsB = (int*)bigBase;
    unsigned int* tmpc = (unsigned int*)bigBase;
    // split tables: tA0(6.4MB) tB0(1.6MB) tA1 tB1 contiguous (16 MB total);
    // they also host tmp (fine records, E*4 = 12.8 MB; dead before transform)
    unsigned short* tA0 = (unsigned short*)(ws + take((size_t)N * 32 * 2));
    unsigned short* tB0 = (unsigned short*)(ws + take((size_t)N * 8 * 2));
    unsigned short* tA1 = (unsigned short*)(ws + take((size_t)N * 32 * 2));
    unsigned short* tB1 = (unsigned short*)(ws + take((size_t)N * 8 * 2));
    unsigned int* tmp = (unsigned int*)tA0;

    // --- build CSR (two-level bucketed counting sort, pow2 ranges) ---
    detect_zero_kernel<<<1, 512, 0, stream>>>(ei, flag, bCount, coarseCnt);
    p3a_scatter<<<P3AGRID, 256, 0, stream>>>(ei, E, flag, bCount, coarseCnt, tmpc);
    p2_scan<<<1, NBALLOC, 0, stream>>>(bCount, bStart, bCursor, starts, E);
    p3b_scatter<<<NCUSED * 8, 256, 0, stream>>>(tmpc, coarseCnt, bCursor, tmp);
    p4_sort<<<NBUSED, 256, 0, stream>>>(tmp, bStart, starts, dis, srcsB, N);

    // --- transform (MFMA, pre-scaled split f16 rows) then 2 hops ---
    const int ntile = (N + 15) / 16;
    const int tblocks = (ntile * 64 + 255) / 256;
    transform_mfma<<<tblocks, 256, 0, stream>>>(feature, weight, dis, tA0, tB0, N);
    const int nwaves = (N + 11) / 12;                     // 12 nodes per wave
    const int nodeBlocks = (nwaves * 64 + 255) / 256;
    prop_hop_kernel<<<nodeBlocks, 256, 0, stream>>>(tA0, tB0, tA1, tB1,
                                                    starts, srcsB, dis, N);
    prop_final_kernel<<<nodeBlocks, 256, 0, stream>>>(tA1, tB1, (float*)d_out,
                                                      starts, srcsB, dis, bias, N);
}

// Round 4
// 373.597 us; speedup vs baseline: 1.2530x; 1.2530x over previous
//
#include <hip/hip_runtime.h>
#include <hip/hip_bf16.h>
#include <hip/hip_fp16.h>
#include <math.h>

// SGC: out = log_softmax( S^2 X W^T + b ), S = D^-1/2 (A+I) D^-1/2
// t0 = dis .* (X W^T) in *f16* (pre-scaled 80 B rows). Round-0 gather
// structure (one wave per dst, 12 groups x 5 lanes x 16B, f16 pk-add,
// fold to lanes 0-4) -- the empirically fastest variant.
// NEW (round 4): each hop runs as TWO SRC-RANGE PASSES. Pass 0 gathers only
// src < 50000 (first 4 MB of the table -> fits per-XCD L2), writes raw
// partial sums; pass 1 gathers src >= 50000 (second 4 MB), adds the partial,
// scales, finishes. Partition by src-half is free in p4 (512-key counting
// sort + mid[]). Partials live in the destination buffers (t1 f16 / out f32).
// Attacks the measured invariant dur ~= L2-miss bytes / 3 TB/s by making
// each pass's gather footprint L2-resident.
// CSR via two-level bucketed counting sort with power-of-2 bucket ranges.

#define N_NODES 100000
#define N_FEAT  128
#define N_CLASS 40

#define RANGE   256           // dsts per fine bucket (pow2: dst>>8)
#define NBALLOC 512
#define NBUSED  391           // ceil(100000/256)
#define RANGE_C 2048          // dsts per coarse bucket (dst>>11)
#define NCALLOC 64
#define NCUSED  49            // ceil(100000/2048)
#define CAP     8704          // fine bucket LDS cap (mean 8192 + ~5.7 sigma)
#define CCAP    67072         // coarse region cap (mean 65536 + ~6 sigma)
#define P3AGRID 1024
#define HALF_SPLIT 50000      // src-range split point (table half = 4 MB)

typedef __attribute__((ext_vector_type(8))) short short8;   // 8 bf16 (4 VGPRs)
typedef __attribute__((ext_vector_type(4))) float floatx4;  // MFMA C/D

// ---------------------------------------------------------------------------
// Detect int32 vs int64 edge_index words; zero counters. 1 block x 512.
__global__ void detect_zero_kernel(const int* __restrict__ ei, int* __restrict__ flag,
                                   int* __restrict__ bucketCount,
                                   int* __restrict__ coarseCnt) {
    int t = threadIdx.x;
    if (t < NBALLOC) bucketCount[t] = 0;
    if (t < NCALLOC) coarseCnt[t] = 0;
    if (t < 64) {
        int nz = (ei[2 * t + 1] != 0) ? 1 : 0;
        unsigned long long b = __ballot(nz);
        if (t == 0) *flag = (b == 0ull) ? 1 : 0;   // 1 => int64 layout
    }
}

__device__ __forceinline__ int edge_word(const int* ei, int elem, int is64) {
    return is64 ? ei[2 * elem] : ei[elem];
}

// P3a: scatter packed records (dstLocalCoarse<<17 | src) into per-block dense
// runs within coarse regions; simultaneously build the fine histogram.
__global__ __launch_bounds__(256) void p3a_scatter(
    const int* __restrict__ ei, int E, const int* __restrict__ flag,
    int* __restrict__ bucketCount, int* __restrict__ coarseCnt,
    unsigned int* __restrict__ tmpc)
{
    __shared__ int hf[NBALLOC];
    __shared__ int hc[NCALLOC];
    __shared__ int basec[NCALLOC];
    __shared__ int curc[NCALLOC];
    int t = threadIdx.x;
    for (int i = t; i < NBALLOC; i += 256) hf[i] = 0;
    if (t < NCALLOC) hc[t] = 0;
    __syncthreads();
    int is64 = *flag;
    int per = (E + gridDim.x - 1) / gridDim.x;
    int e0 = blockIdx.x * per;
    int e1 = min(E, e0 + per);
    for (int e = e0 + t; e < e1; e += 256) {
        int c = edge_word(ei, E + e, is64);
        atomicAdd(&hf[c >> 8], 1);
        atomicAdd(&hc[c >> 11], 1);
    }
    __syncthreads();
    if (t < NCALLOC) {
        basec[t] = hc[t] ? atomicAdd(&coarseCnt[t], hc[t]) : 0;
        curc[t] = 0;
    }
    for (int i = t; i < NBALLOC; i += 256)
        if (hf[i]) atomicAdd(&bucketCount[i], hf[i]);
    __syncthreads();
    for (int e = e0 + t; e < e1; e += 256) {
        int c = edge_word(ei, E + e, is64);
        int r = edge_word(ei, e, is64);
        int cb = c >> 11;
        int p = basec[cb] + atomicAdd(&curc[cb], 1);
        if (p < CCAP)
            tmpc[(size_t)cb * CCAP + p] = ((unsigned)(c & 2047) << 17) | (unsigned)r;
    }
}

// P2: scan fine counts -> bucketStart/bucketCursor; starts[N]=E.
__global__ __launch_bounds__(NBALLOC) void p2_scan(
    const int* __restrict__ bucketCount, int* __restrict__ bucketStart,
    int* __restrict__ bucketCursor, int* __restrict__ starts, int E)
{
    __shared__ int s[NBALLOC];
    int t = threadIdx.x;
    int v = bucketCount[t];
    s[t] = v;
    __syncthreads();
    for (int o = 1; o < NBALLOC; o <<= 1) {
        int y = (t >= o) ? s[t - o] : 0;
        __syncthreads();
        s[t] += y;
        __syncthreads();
    }
    int incl = s[t], excl = incl - v;
    bucketStart[t] = excl;
    bucketCursor[t] = excl;
    if (t == NBALLOC - 1) { bucketStart[NBALLOC] = incl; starts[N_NODES] = E; }
}

// P3b: 8 blocks per coarse bucket; re-scatter into its 8 fine buckets.
__global__ __launch_bounds__(256) void p3b_scatter(
    const unsigned int* __restrict__ tmpc, const int* __restrict__ coarseCnt,
    int* __restrict__ bucketCursor, unsigned int* __restrict__ tmp)
{
    __shared__ int fh[8];
    __shared__ int fb[8];
    __shared__ int fc[8];
    int cb = blockIdx.x >> 3;
    int j = blockIdx.x & 7;
    int t = threadIdx.x;
    int cnt = coarseCnt[cb];
    if (cnt > CCAP) cnt = CCAP;
    int chunk = (cnt + 7) >> 3;
    int r0 = j * chunk;
    int r1 = min(cnt, r0 + chunk);
    if (t < 8) fh[t] = 0;
    __syncthreads();
    const unsigned int* rec = tmpc + (size_t)cb * CCAP;
    for (int i = r0 + t; i < r1; i += 256) {
        int dlc = (int)(rec[i] >> 17);
        atomicAdd(&fh[dlc >> 8], 1);
    }
    __syncthreads();
    if (t < 8) {
        fb[t] = fh[t] ? atomicAdd(&bucketCursor[cb * 8 + t], fh[t]) : 0;
        fc[t] = 0;
    }
    __syncthreads();
    for (int i = r0 + t; i < r1; i += 256) {
        unsigned v = rec[i];
        int dlc = (int)(v >> 17);
        unsigned src = v & 0x1FFFFu;
        int fi = dlc >> 8;
        int dlf = dlc & 255;
        int p = fb[fi] + atomicAdd(&fc[fi], 1);
        tmp[p] = ((unsigned)dlf << 24) | src;
    }
}

// P4: per-fine-bucket LDS counting sort with 512 keys (dlf*2 + srcHalf) ->
// starts, mid (end of half0 / begin of half1), dis, srcsB (byte offsets,
// src*80, coalesced). tmp is read twice (streaming).
__global__ __launch_bounds__(256) void p4_sort(
    const unsigned int* __restrict__ tmp, const int* __restrict__ bucketStart,
    int* __restrict__ starts, int* __restrict__ mid, float* __restrict__ dis,
    int* __restrict__ srcsB, int N)
{
    __shared__ int srt[CAP];
    __shared__ int hist[512];
    __shared__ int sc[256];
    __shared__ int cur[512];
    int b = blockIdx.x, t = threadIdx.x;
    int g0 = b * RANGE;
    int gcnt = N - g0;
    if (gcnt > RANGE) gcnt = RANGE;
    int base = bucketStart[b];
    int n = bucketStart[b + 1] - base;
    hist[t] = 0;
    hist[t + 256] = 0;
    __syncthreads();
    for (int i = t; i < n; i += 256) {
        unsigned v = tmp[base + i];
        int key = (int)((v >> 24) << 1) | (((v & 0xFFFFFFu) >= HALF_SPLIT) ? 1 : 0);
        atomicAdd(&hist[key], 1);
    }
    __syncthreads();
    int c0 = hist[2 * t], c1 = hist[2 * t + 1];
    sc[t] = c0 + c1;
    __syncthreads();
    for (int o = 1; o < 256; o <<= 1) {
        int y = (t >= o) ? sc[t - o] : 0;
        __syncthreads();
        sc[t] += y;
        __syncthreads();
    }
    int excl = sc[t] - (c0 + c1);
    if (t < gcnt) {
        starts[g0 + t] = base + excl;
        mid[g0 + t] = base + excl + c0;
        dis[g0 + t] = rsqrtf((float)(c0 + c1 + 1));   // +1 self-loop
    }
    cur[2 * t] = excl;
    cur[2 * t + 1] = excl + c0;
    __syncthreads();
    if (n <= CAP) {
        for (int i = t; i < n; i += 256) {
            unsigned v = tmp[base + i];
            int src = (int)(v & 0xFFFFFFu);
            int key = (int)((v >> 24) << 1) | ((src >= HALF_SPLIT) ? 1 : 0);
            int p = atomicAdd(&cur[key], 1);
            srt[p] = src * 80;                   // pre-scaled byte offset
        }
        __syncthreads();
        for (int i = t; i < n; i += 256) srcsB[base + i] = srt[i];
    } else {
        // overflow fallback (statistically never taken)
        for (int i = t; i < n; i += 256) {
            unsigned v = tmp[base + i];
            int src = (int)(v & 0xFFFFFFu);
            int key = (int)((v >> 24) << 1) | ((src >= HALF_SPLIT) ? 1 : 0);
            int p = atomicAdd(&cur[key], 1);
            srcsB[base + p] = src * 80;
        }
    }
}

// ---------------------------------------------------------------------------
__device__ __forceinline__ unsigned short f2bf(float f) {   // RTN f32 -> bf16
    unsigned u = __float_as_uint(f);
    unsigned r = u + 0x7FFFu + ((u >> 16) & 1u);
    return (unsigned short)(r >> 16);
}
__device__ __forceinline__ __half2 u2h(unsigned w) {
    union { unsigned u; __half2 h; } c; c.u = w; return c.h;
}
__device__ __forceinline__ unsigned h2u(__half2 h) {
    union { unsigned u; __half2 h; } c; c.h = h; return c.u;
}

// t0 = dis .* (X @ W^T), f16, row stride 40 (80 B). One wave per 16 nodes.
// MFMA on bf16 inputs (f32 accumulate), output stored f16.
__global__ __launch_bounds__(256) void transform_mfma(
    const float* __restrict__ x, const float* __restrict__ W,
    const float* __restrict__ dis, unsigned short* __restrict__ t0, int N)
{
    __shared__ uint4 Wl[3 * 4 * 64];        // B frags, bf16-packed: 12 KiB
    int t = threadIdx.x;
    for (int i = t; i < 3 * 4 * 64; i += 256) {
        int lane = i & 63;
        int kc = (i >> 6) & 3;
        int nt = i >> 8;
        int n = nt * 16 + (lane & 15);
        int k = kc * 32 + (lane >> 4) * 8;
        union { unsigned short s[8]; uint4 v; } u;
        #pragma unroll
        for (int j = 0; j < 8; ++j)
            u.s[j] = (n < N_CLASS) ? f2bf(W[n * N_FEAT + k + j]) : (unsigned short)0;
        Wl[i] = u.v;
    }
    __syncthreads();
    int wave = (blockIdx.x * blockDim.x + threadIdx.x) >> 6;
    int lane = threadIdx.x & 63;
    int ntile = (N + 15) / 16;
    if (wave >= ntile) return;
    int m = lane & 15, quad = lane >> 4;
    int row = wave * 16 + m;
    const short8* Wf = reinterpret_cast<const short8*>(Wl);
    floatx4 acc0 = {0.f, 0.f, 0.f, 0.f}, acc1 = acc0, acc2 = acc0;
    #pragma unroll
    for (int kc = 0; kc < 4; ++kc) {
        const float4* xr = reinterpret_cast<const float4*>(
            x + (size_t)row * N_FEAT + kc * 32 + quad * 8);
        float4 a0 = xr[0], a1 = xr[1];
        short8 af;
        af[0] = f2bf(a0.x); af[1] = f2bf(a0.y); af[2] = f2bf(a0.z); af[3] = f2bf(a0.w);
        af[4] = f2bf(a1.x); af[5] = f2bf(a1.y); af[6] = f2bf(a1.z); af[7] = f2bf(a1.w);
        short8 b0 = Wf[(0 * 4 + kc) * 64 + lane];
        short8 b1 = Wf[(1 * 4 + kc) * 64 + lane];
        short8 b2 = Wf[(2 * 4 + kc) * 64 + lane];
        acc0 = __builtin_amdgcn_mfma_f32_16x16x32_bf16(af, b0, acc0, 0, 0, 0);
        acc1 = __builtin_amdgcn_mfma_f32_16x16x32_bf16(af, b1, acc1, 0, 0, 0);
        acc2 = __builtin_amdgcn_mfma_f32_16x16x32_bf16(af, b2, acc2, 0, 0, 0);
    }
    #pragma unroll
    for (int r = 0; r < 4; ++r) {
        int rw = wave * 16 + quad * 4 + r;
        float ds = dis[rw];
        unsigned short* tr = t0 + (size_t)rw * N_CLASS;
        tr[m] = __half_as_ushort(__float2half(ds * acc0[r]));
        tr[16 + m] = __half_as_ushort(__float2half(ds * acc1[r]));
        if (m < 8) tr[32 + m] = __half_as_ushort(__float2half(ds * acc2[r]));
    }
}

// 12-group fold: groups 0..11 (lanes 0-59) summed into lanes 0-4, packed f16.
__device__ __forceinline__ __half2 foldh(__half2 a, int lane) {
    a = __hadd2(a, u2h((unsigned)__shfl((int)h2u(a), lane + 30)));
    a = __hadd2(a, u2h((unsigned)__shfl((int)h2u(a), lane + 15)));
    __half2 u = u2h((unsigned)__shfl((int)h2u(a), lane + 5));
    __half2 v = u2h((unsigned)__shfl((int)h2u(a), lane + 10));
    return __hadd2(__hadd2(a, u), v);
}

// Shared gather (round-0 structure): 12 groups x 5 lanes x 16B; packed-f16
// accumulate, 2 banks. After fold, lanes 0-4 hold classes [sl*8, sl*8+8).
// Parametrized by edge range [eBp[d], eEp[d]) and SELF (seed with row d).
#define GATHER12H(tin, eBp, eEp, SELF)                                         \
    int wave = (blockIdx.x * blockDim.x + threadIdx.x) >> 6;                   \
    int lane = threadIdx.x & 63;                                               \
    if (wave >= N) return;                                                     \
    int d = wave;                                                              \
    int g = lane / 5;                       /* 0..12 (lanes 60-63 ghost) */    \
    int sl = lane - g * 5;                  /* 0..4 */                         \
    int slo = sl << 4;                      /* byte offset within row */       \
    int e0 = (eBp)[d], e1 = (eEp)[d];                                          \
    const char* tb = (const char*)(tin);                                       \
    __half2 z2 = u2h(0u);                                                      \
    __half2 A0 = z2, A1 = z2, A2 = z2, A3 = z2;                                \
    __half2 B0 = z2, B1 = z2, B2 = z2, B3 = z2;                                \
    if (SELF && lane < 5) {                 /* self term row d */              \
        uint4 r = *reinterpret_cast<const uint4*>(tb + d * 80 + slo);          \
        A0 = u2h(r.x); A1 = u2h(r.y); A2 = u2h(r.z); A3 = u2h(r.w);            \
    }                                                                          \
    int gg = (g < 12) ? g : 0;              /* ghosts shadow group 0 */        \
    int e = e0;                                                                \
    for (; e + 24 <= e1; e += 24) {         /* unmasked: 2 gathers in flight */\
        int o1 = srcsB[e + gg];                                                \
        int o2 = srcsB[e + 12 + gg];                                           \
        uint4 r1 = *reinterpret_cast<const uint4*>(tb + (size_t)(unsigned)o1 + slo); \
        uint4 r2 = *reinterpret_cast<const uint4*>(tb + (size_t)(unsigned)o2 + slo); \
        A0 = __hadd2(A0, u2h(r1.x)); A1 = __hadd2(A1, u2h(r1.y));              \
        A2 = __hadd2(A2, u2h(r1.z)); A3 = __hadd2(A3, u2h(r1.w));              \
        B0 = __hadd2(B0, u2h(r2.x)); B1 = __hadd2(B1, u2h(r2.y));              \
        B2 = __hadd2(B2, u2h(r2.z)); B3 = __hadd2(B3, u2h(r2.w));              \
    }                                                                          \
    for (; e < e1; e += 12) {               /* masked tail, <=2 iters */       \
        int ee = e + gg;                                                       \
        int o1 = srcsB[min(ee, e1 - 1)];                                       \
        uint4 r1 = *reinterpret_cast<const uint4*>(tb + (size_t)(unsigned)o1 + slo); \
        if (!(ee < e1 && g < 12)) { r1.x = 0u; r1.y = 0u; r1.z = 0u; r1.w = 0u; } \
        A0 = __hadd2(A0, u2h(r1.x)); A1 = __hadd2(A1, u2h(r1.y));              \
        A2 = __hadd2(A2, u2h(r1.z)); A3 = __hadd2(A3, u2h(r1.w));              \
    }                                                                          \
    A0 = __hadd2(A0, B0); A1 = __hadd2(A1, B1);                                \
    A2 = __hadd2(A2, B2); A3 = __hadd2(A3, B3);                                \
    A0 = foldh(A0, lane); A1 = foldh(A1, lane);                                \
    A2 = foldh(A2, lane); A3 = foldh(A3, lane);

// Middle hop, pass 0 (src < HALF): tout[d] = raw f16 partial (t[d] + sum).
__global__ __launch_bounds__(256) void prop_hop0(
    const unsigned short* __restrict__ tin, unsigned short* __restrict__ tout,
    const int* __restrict__ starts, const int* __restrict__ mid,
    const int* __restrict__ srcsB, int N)
{
    GATHER12H(tin, starts, mid, 1)
    if (lane < 5) {
        uint4 o;
        o.x = h2u(A0); o.y = h2u(A1); o.z = h2u(A2); o.w = h2u(A3);
        *reinterpret_cast<uint4*>((char*)tout + d * 80 + slo) = o;
    }
}

// Middle hop, pass 1 (src >= HALF): tout[d] = f16( dd^2 * (partial + sum) ).
__global__ __launch_bounds__(256) void prop_hop1(
    const unsigned short* __restrict__ tin, unsigned short* __restrict__ tout,
    const int* __restrict__ starts, const int* __restrict__ mid,
    const int* __restrict__ srcsB, const float* __restrict__ dis, int N)
{
    GATHER12H(tin, mid, starts + 1, 0)
    if (lane < 5) {
        uint4 pr = *reinterpret_cast<const uint4*>((const char*)tout + d * 80 + slo);
        A0 = __hadd2(A0, u2h(pr.x)); A1 = __hadd2(A1, u2h(pr.y));
        A2 = __hadd2(A2, u2h(pr.z)); A3 = __hadd2(A3, u2h(pr.w));
        float dd = dis[d];
        float sc = dd * dd;
        float2 f0 = __half22float2(A0), f1 = __half22float2(A1);
        float2 f2 = __half22float2(A2), f3 = __half22float2(A3);
        uint4 o;
        o.x = h2u(__floats2half2_rn(sc * f0.x, sc * f0.y));
        o.y = h2u(__floats2half2_rn(sc * f1.x, sc * f1.y));
        o.z = h2u(__floats2half2_rn(sc * f2.x, sc * f2.y));
        o.w = h2u(__floats2half2_rn(sc * f3.x, sc * f3.y));
        *reinterpret_cast<uint4*>((char*)tout + d * 80 + slo) = o;
    }
}

// Final hop, pass 0: out[d][*] = raw f32 partial (t[d] + sum over half0).
__global__ __launch_bounds__(256) void prop_fin0(
    const unsigned short* __restrict__ tin, float* __restrict__ out,
    const int* __restrict__ starts, const int* __restrict__ mid,
    const int* __restrict__ srcsB, int N)
{
    GATHER12H(tin, starts, mid, 1)
    if (lane < 5) {
        float2 f0 = __half22float2(A0), f1 = __half22float2(A1);
        float2 f2 = __half22float2(A2), f3 = __half22float2(A3);
        float* ro = out + (size_t)d * N_CLASS + sl * 8;
        *reinterpret_cast<float4*>(ro)     = make_float4(f0.x, f0.y, f1.x, f1.y);
        *reinterpret_cast<float4*>(ro + 4) = make_float4(f2.x, f2.y, f3.x, f3.y);
    }
}

// Final hop, pass 1: sum over half1 + partial, bias + log_softmax, write out.
__global__ __launch_bounds__(256) void prop_fin1(
    const unsigned short* __restrict__ tin, float* __restrict__ out,
    const int* __restrict__ starts, const int* __restrict__ mid,
    const int* __restrict__ srcsB, const float* __restrict__ dis,
    const float* __restrict__ bias, int N)
{
    GATHER12H(tin, mid, starts + 1, 0)
    float dd = dis[d];
    const float* pp = out + (size_t)d * N_CLASS + sl * 8;
    float4 plo = *reinterpret_cast<const float4*>(pp);
    float4 phi = *reinterpret_cast<const float4*>(pp + 4);
    float4 blo = reinterpret_cast<const float4*>(bias)[sl * 2];       // sl<5
    float4 bhi = reinterpret_cast<const float4*>(bias)[sl * 2 + 1];
    float2 f0 = __half22float2(A0), f1 = __half22float2(A1);
    float2 f2 = __half22float2(A2), f3 = __half22float2(A3);
    float v0 = dd * (plo.x + f0.x) + blo.x, v1 = dd * (plo.y + f0.y) + blo.y;
    float v2 = dd * (plo.z + f1.x) + blo.z, v3 = dd * (plo.w + f1.y) + blo.w;
    float v4 = dd * (phi.x + f2.x) + bhi.x, v5 = dd * (phi.y + f2.y) + bhi.y;
    float v6 = dd * (phi.z + f3.x) + bhi.z, v7 = dd * (phi.w + f3.y) + bhi.w;
    float mx = fmaxf(fmaxf(fmaxf(v0, v1), fmaxf(v2, v3)),
                     fmaxf(fmaxf(v4, v5), fmaxf(v6, v7)));
    if (lane >= 5) mx = -INFINITY;
    #pragma unroll
    for (int o = 4; o; o >>= 1) mx = fmaxf(mx, __shfl_xor(mx, o, 8));
    float s = 0.f;
    if (lane < 5) {
        s = expf(v0 - mx) + expf(v1 - mx) + expf(v2 - mx) + expf(v3 - mx)
          + expf(v4 - mx) + expf(v5 - mx) + expf(v6 - mx) + expf(v7 - mx);
    }
    #pragma unroll
    for (int o = 4; o; o >>= 1) s += __shfl_xor(s, o, 8);
    if (lane < 5) {
        float ls = mx + logf(s);
        float* ro = out + (size_t)d * N_CLASS + sl * 8;
        *reinterpret_cast<float4*>(ro)     = make_float4(v0 - ls, v1 - ls, v2 - ls, v3 - ls);
        *reinterpret_cast<float4*>(ro + 4) = make_float4(v4 - ls, v5 - ls, v6 - ls, v7 - ls);
    }
}

// ---------------------------------------------------------------------------
extern "C" void kernel_launch(void* const* d_in, const int* in_sizes, int n_in,
                              void* d_out, int out_size, void* d_ws, size_t ws_size,
                              hipStream_t stream) {
    const float* feature = (const float*)d_in[0];   // [N, 128]
    const float* weight  = (const float*)d_in[1];   // [40, 128]
    const float* bias    = (const float*)d_in[2];   // [40]
    const int*   ei      = (const int*)d_in[3];     // [2, E] (int32 or int64 words)
    const int N = N_NODES;
    const int E = in_sizes[3] / 2;

    size_t off = 0;
    auto take = [&](size_t bytes) { size_t o = off; off += (bytes + 255) & ~(size_t)255; return o; };
    char* ws = (char*)d_ws;
    int*   flag      = (int*)  (ws + take(4));
    int*   bCount    = (int*)  (ws + take((size_t)NBALLOC * 4));
    int*   bStart    = (int*)  (ws + take((size_t)(NBALLOC + 1) * 4));
    int*   bCursor   = (int*)  (ws + take((size_t)NBALLOC * 4));
    int*   coarseCnt = (int*)  (ws + take((size_t)NCALLOC * 4));
    int*   starts    = (int*)  (ws + take((size_t)(N + 1) * 4));
    int*   mid       = (int*)  (ws + take((size_t)N * 4));
    float* dis       = (float*)(ws + take((size_t)N * 4));
    // srcsB region also hosts tmpc (coarse records): tmpc dead before p4 writes srcsB
    size_t srcsBytes = (size_t)E * 4;
    size_t tmpcBytes = (size_t)NCALLOC * CCAP * 4;
    size_t bigBytes = srcsBytes > tmpcBytes ? srcsBytes : tmpcBytes;
    char* bigBase = ws + take(bigBytes);
    int* srcsB = (int*)bigBase;
    unsigned int* tmpc = (unsigned int*)bigBase;
    // t0+t1 (16 MB contiguous) also host tmp (fine records, E*4 = 12.8 MB)
    unsigned short* t0 = (unsigned short*)(ws + take((size_t)N * N_CLASS * 2));
    unsigned short* t1 = (unsigned short*)(ws + take((size_t)N * N_CLASS * 2));
    unsigned int* tmp = (unsigned int*)t0;

    // --- build CSR (two-level bucketed counting sort, pow2 ranges) ---
    detect_zero_kernel<<<1, 512, 0, stream>>>(ei, flag, bCount, coarseCnt);
    p3a_scatter<<<P3AGRID, 256, 0, stream>>>(ei, E, flag, bCount, coarseCnt, tmpc);
    p2_scan<<<1, NBALLOC, 0, stream>>>(bCount, bStart, bCursor, starts, E);
    p3b_scatter<<<NCUSED * 8, 256, 0, stream>>>(tmpc, coarseCnt, bCursor, tmp);
    p4_sort<<<NBUSED, 256, 0, stream>>>(tmp, bStart, starts, mid, dis, srcsB, N);

    // --- transform (MFMA, pre-scaled f16 rows) then 2 hops x 2 src-passes ---
    const int ntile = (N + 15) / 16;
    const int tblocks = (ntile * 64 + 255) / 256;
    transform_mfma<<<tblocks, 256, 0, stream>>>(feature, weight, dis, t0, N);
    const int nodeBlocks = (N * 64 + 255) / 256;           // one wave per node
    prop_hop0<<<nodeBlocks, 256, 0, stream>>>(t0, t1, starts, mid, srcsB, N);
    prop_hop1<<<nodeBlocks, 256, 0, stream>>>(t0, t1, starts, mid, srcsB, dis, N);
    prop_fin0<<<nodeBlocks, 256, 0, stream>>>(t1, (float*)d_out, starts, mid, srcsB, N);
    prop_fin1<<<nodeBlocks, 256, 0, stream>>>(t1, (float*)d_out, starts, mid, srcsB,
                                              dis, bias, N);
}

// Round 5
// 332.636 us; speedup vs baseline: 1.4073x; 1.1231x over previous
//
#include <hip/hip_runtime.h>
#include <hip/hip_bf16.h>
#include <hip/hip_fp16.h>
#include <math.h>

// SGC: out = log_softmax( S^2 X W^T + b ), S = D^-1/2 (A+I) D^-1/2
// t0 = dis .* (X W^T) in *f16* (pre-scaled 80 B rows).
// Round 5 = round-4's SRC-RANGE PASS SPLIT (memory fix: each pass gathers
// only one 4 MB half of the table -> L2-resident, FETCH 190->54 MB/pass)
//   COMBINED WITH
// round-1's GROUP-PER-NODE gather (VALU fix: 5-lane group per dst node,
// 12 nodes/wave, f32 accumulation, no folds; VALUBusy 84->16%).
// Self-term handled in the pass whose half contains d (it is a gather too).
// Partials live in the destination buffers (t1 f16 / out f32).
// CSR via two-level bucketed counting sort; p4 uses 512 keys
// (dstLocal*2 + srcHalf) to partition each dst's edges by src half.

#define N_NODES 100000
#define N_FEAT  128
#define N_CLASS 40

#define RANGE   256           // dsts per fine bucket (pow2: dst>>8)
#define NBALLOC 512
#define NBUSED  391           // ceil(100000/256)
#define RANGE_C 2048          // dsts per coarse bucket (dst>>11)
#define NCALLOC 64
#define NCUSED  49            // ceil(100000/2048)
#define CAP     8704          // fine bucket LDS cap (mean 8192 + ~5.7 sigma)
#define CCAP    67072         // coarse region cap (mean 65536 + ~6 sigma)
#define P3AGRID 1024
#define HALF_SPLIT 50000      // src-range split point (table half = 4 MB)

typedef __attribute__((ext_vector_type(8))) short short8;   // 8 bf16 (4 VGPRs)
typedef __attribute__((ext_vector_type(4))) float floatx4;  // MFMA C/D

// ---------------------------------------------------------------------------
// Detect int32 vs int64 edge_index words; zero counters. 1 block x 512.
__global__ void detect_zero_kernel(const int* __restrict__ ei, int* __restrict__ flag,
                                   int* __restrict__ bucketCount,
                                   int* __restrict__ coarseCnt) {
    int t = threadIdx.x;
    if (t < NBALLOC) bucketCount[t] = 0;
    if (t < NCALLOC) coarseCnt[t] = 0;
    if (t < 64) {
        int nz = (ei[2 * t + 1] != 0) ? 1 : 0;
        unsigned long long b = __ballot(nz);
        if (t == 0) *flag = (b == 0ull) ? 1 : 0;   // 1 => int64 layout
    }
}

__device__ __forceinline__ int edge_word(const int* ei, int elem, int is64) {
    return is64 ? ei[2 * elem] : ei[elem];
}

// P3a: scatter packed records (dstLocalCoarse<<17 | src) into per-block dense
// runs within coarse regions; simultaneously build the fine histogram.
__global__ __launch_bounds__(256) void p3a_scatter(
    const int* __restrict__ ei, int E, const int* __restrict__ flag,
    int* __restrict__ bucketCount, int* __restrict__ coarseCnt,
    unsigned int* __restrict__ tmpc)
{
    __shared__ int hf[NBALLOC];
    __shared__ int hc[NCALLOC];
    __shared__ int basec[NCALLOC];
    __shared__ int curc[NCALLOC];
    int t = threadIdx.x;
    for (int i = t; i < NBALLOC; i += 256) hf[i] = 0;
    if (t < NCALLOC) hc[t] = 0;
    __syncthreads();
    int is64 = *flag;
    int per = (E + gridDim.x - 1) / gridDim.x;
    int e0 = blockIdx.x * per;
    int e1 = min(E, e0 + per);
    for (int e = e0 + t; e < e1; e += 256) {
        int c = edge_word(ei, E + e, is64);
        atomicAdd(&hf[c >> 8], 1);
        atomicAdd(&hc[c >> 11], 1);
    }
    __syncthreads();
    if (t < NCALLOC) {
        basec[t] = hc[t] ? atomicAdd(&coarseCnt[t], hc[t]) : 0;
        curc[t] = 0;
    }
    for (int i = t; i < NBALLOC; i += 256)
        if (hf[i]) atomicAdd(&bucketCount[i], hf[i]);
    __syncthreads();
    for (int e = e0 + t; e < e1; e += 256) {
        int c = edge_word(ei, E + e, is64);
        int r = edge_word(ei, e, is64);
        int cb = c >> 11;
        int p = basec[cb] + atomicAdd(&curc[cb], 1);
        if (p < CCAP)
            tmpc[(size_t)cb * CCAP + p] = ((unsigned)(c & 2047) << 17) | (unsigned)r;
    }
}

// P2: scan fine counts -> bucketStart/bucketCursor; starts[N]=E.
__global__ __launch_bounds__(NBALLOC) void p2_scan(
    const int* __restrict__ bucketCount, int* __restrict__ bucketStart,
    int* __restrict__ bucketCursor, int* __restrict__ starts, int E)
{
    __shared__ int s[NBALLOC];
    int t = threadIdx.x;
    int v = bucketCount[t];
    s[t] = v;
    __syncthreads();
    for (int o = 1; o < NBALLOC; o <<= 1) {
        int y = (t >= o) ? s[t - o] : 0;
        __syncthreads();
        s[t] += y;
        __syncthreads();
    }
    int incl = s[t], excl = incl - v;
    bucketStart[t] = excl;
    bucketCursor[t] = excl;
    if (t == NBALLOC - 1) { bucketStart[NBALLOC] = incl; starts[N_NODES] = E; }
}

// P3b: 8 blocks per coarse bucket; re-scatter into its 8 fine buckets.
__global__ __launch_bounds__(256) void p3b_scatter(
    const unsigned int* __restrict__ tmpc, const int* __restrict__ coarseCnt,
    int* __restrict__ bucketCursor, unsigned int* __restrict__ tmp)
{
    __shared__ int fh[8];
    __shared__ int fb[8];
    __shared__ int fc[8];
    int cb = blockIdx.x >> 3;
    int j = blockIdx.x & 7;
    int t = threadIdx.x;
    int cnt = coarseCnt[cb];
    if (cnt > CCAP) cnt = CCAP;
    int chunk = (cnt + 7) >> 3;
    int r0 = j * chunk;
    int r1 = min(cnt, r0 + chunk);
    if (t < 8) fh[t] = 0;
    __syncthreads();
    const unsigned int* rec = tmpc + (size_t)cb * CCAP;
    for (int i = r0 + t; i < r1; i += 256) {
        int dlc = (int)(rec[i] >> 17);
        atomicAdd(&fh[dlc >> 8], 1);
    }
    __syncthreads();
    if (t < 8) {
        fb[t] = fh[t] ? atomicAdd(&bucketCursor[cb * 8 + t], fh[t]) : 0;
        fc[t] = 0;
    }
    __syncthreads();
    for (int i = r0 + t; i < r1; i += 256) {
        unsigned v = rec[i];
        int dlc = (int)(v >> 17);
        unsigned src = v & 0x1FFFFu;
        int fi = dlc >> 8;
        int dlf = dlc & 255;
        int p = fb[fi] + atomicAdd(&fc[fi], 1);
        tmp[p] = ((unsigned)dlf << 24) | src;
    }
}

// P4: per-fine-bucket LDS counting sort with 512 keys (dlf*2 + srcHalf) ->
// starts, mid (end of half0 / begin of half1), dis, srcsB (byte offsets,
// src*80, coalesced). tmp is read twice (streaming).
__global__ __launch_bounds__(256) void p4_sort(
    const unsigned int* __restrict__ tmp, const int* __restrict__ bucketStart,
    int* __restrict__ starts, int* __restrict__ mid, float* __restrict__ dis,
    int* __restrict__ srcsB, int N)
{
    __shared__ int srt[CAP];
    __shared__ int hist[512];
    __shared__ int sc[256];
    __shared__ int cur[512];
    int b = blockIdx.x, t = threadIdx.x;
    int g0 = b * RANGE;
    int gcnt = N - g0;
    if (gcnt > RANGE) gcnt = RANGE;
    int base = bucketStart[b];
    int n = bucketStart[b + 1] - base;
    hist[t] = 0;
    hist[t + 256] = 0;
    __syncthreads();
    for (int i = t; i < n; i += 256) {
        unsigned v = tmp[base + i];
        int key = (int)((v >> 24) << 1) | (((v & 0xFFFFFFu) >= HALF_SPLIT) ? 1 : 0);
        atomicAdd(&hist[key], 1);
    }
    __syncthreads();
    int c0 = hist[2 * t], c1 = hist[2 * t + 1];
    sc[t] = c0 + c1;
    __syncthreads();
    for (int o = 1; o < 256; o <<= 1) {
        int y = (t >= o) ? sc[t - o] : 0;
        __syncthreads();
        sc[t] += y;
        __syncthreads();
    }
    int excl = sc[t] - (c0 + c1);
    if (t < gcnt) {
        starts[g0 + t] = base + excl;
        mid[g0 + t] = base + excl + c0;
        dis[g0 + t] = rsqrtf((float)(c0 + c1 + 1));   // +1 self-loop
    }
    cur[2 * t] = excl;
    cur[2 * t + 1] = excl + c0;
    __syncthreads();
    if (n <= CAP) {
        for (int i = t; i < n; i += 256) {
            unsigned v = tmp[base + i];
            int src = (int)(v & 0xFFFFFFu);
            int key = (int)((v >> 24) << 1) | ((src >= HALF_SPLIT) ? 1 : 0);
            int p = atomicAdd(&cur[key], 1);
            srt[p] = src * 80;                   // pre-scaled byte offset
        }
        __syncthreads();
        for (int i = t; i < n; i += 256) srcsB[base + i] = srt[i];
    } else {
        // overflow fallback (statistically never taken)
        for (int i = t; i < n; i += 256) {
            unsigned v = tmp[base + i];
            int src = (int)(v & 0xFFFFFFu);
            int key = (int)((v >> 24) << 1) | ((src >= HALF_SPLIT) ? 1 : 0);
            int p = atomicAdd(&cur[key], 1);
            srcsB[base + p] = src * 80;
        }
    }
}

// ---------------------------------------------------------------------------
__device__ __forceinline__ unsigned short f2bf(float f) {   // RTN f32 -> bf16
    unsigned u = __float_as_uint(f);
    unsigned r = u + 0x7FFFu + ((u >> 16) & 1u);
    return (unsigned short)(r >> 16);
}
__device__ __forceinline__ __half2 u2h(unsigned w) {
    union { unsigned u; __half2 h; } c; c.u = w; return c.h;
}
__device__ __forceinline__ unsigned h2u(__half2 h) {
    union { unsigned u; __half2 h; } c; c.h = h; return c.u;
}

// t0 = dis .* (X @ W^T), f16, row stride 40 (80 B). One wave per 16 nodes.
// MFMA on bf16 inputs (f32 accumulate), output stored f16.
__global__ __launch_bounds__(256) void transform_mfma(
    const float* __restrict__ x, const float* __restrict__ W,
    const float* __restrict__ dis, unsigned short* __restrict__ t0, int N)
{
    __shared__ uint4 Wl[3 * 4 * 64];        // B frags, bf16-packed: 12 KiB
    int t = threadIdx.x;
    for (int i = t; i < 3 * 4 * 64; i += 256) {
        int lane = i & 63;
        int kc = (i >> 6) & 3;
        int nt = i >> 8;
        int n = nt * 16 + (lane & 15);
        int k = kc * 32 + (lane >> 4) * 8;
        union { unsigned short s[8]; uint4 v; } u;
        #pragma unroll
        for (int j = 0; j < 8; ++j)
            u.s[j] = (n < N_CLASS) ? f2bf(W[n * N_FEAT + k + j]) : (unsigned short)0;
        Wl[i] = u.v;
    }
    __syncthreads();
    int wave = (blockIdx.x * blockDim.x + threadIdx.x) >> 6;
    int lane = threadIdx.x & 63;
    int ntile = (N + 15) / 16;
    if (wave >= ntile) return;
    int m = lane & 15, quad = lane >> 4;
    int row = wave * 16 + m;
    const short8* Wf = reinterpret_cast<const short8*>(Wl);
    floatx4 acc0 = {0.f, 0.f, 0.f, 0.f}, acc1 = acc0, acc2 = acc0;
    #pragma unroll
    for (int kc = 0; kc < 4; ++kc) {
        const float4* xr = reinterpret_cast<const float4*>(
            x + (size_t)row * N_FEAT + kc * 32 + quad * 8);
        float4 a0 = xr[0], a1 = xr[1];
        short8 af;
        af[0] = f2bf(a0.x); af[1] = f2bf(a0.y); af[2] = f2bf(a0.z); af[3] = f2bf(a0.w);
        af[4] = f2bf(a1.x); af[5] = f2bf(a1.y); af[6] = f2bf(a1.z); af[7] = f2bf(a1.w);
        short8 b0 = Wf[(0 * 4 + kc) * 64 + lane];
        short8 b1 = Wf[(1 * 4 + kc) * 64 + lane];
        short8 b2 = Wf[(2 * 4 + kc) * 64 + lane];
        acc0 = __builtin_amdgcn_mfma_f32_16x16x32_bf16(af, b0, acc0, 0, 0, 0);
        acc1 = __builtin_amdgcn_mfma_f32_16x16x32_bf16(af, b1, acc1, 0, 0, 0);
        acc2 = __builtin_amdgcn_mfma_f32_16x16x32_bf16(af, b2, acc2, 0, 0, 0);
    }
    #pragma unroll
    for (int r = 0; r < 4; ++r) {
        int rw = wave * 16 + quad * 4 + r;
        float ds = dis[rw];
        unsigned short* tr = t0 + (size_t)rw * N_CLASS;
        tr[m] = __half_as_ushort(__float2half(ds * acc0[r]));
        tr[16 + m] = __half_as_ushort(__float2half(ds * acc1[r]));
        if (m < 8) tr[32 + m] = __half_as_ushort(__float2half(ds * acc2[r]));
    }
}

// ---------------------------------------------------------------------------
// Group-per-node gather: 12 groups x 5 lanes per wave; lane sl owns bytes
// [16*sl, 16*sl+16) of the 80 B row. f32 accumulation in two banks.
struct F8 { float v0, v1, v2, v3, v4, v5, v6, v7; };

__device__ __forceinline__ void acc8(F8& a, uint4 r) {
    float2 f0 = __half22float2(u2h(r.x));
    float2 f1 = __half22float2(u2h(r.y));
    float2 f2 = __half22float2(u2h(r.z));
    float2 f3 = __half22float2(u2h(r.w));
    a.v0 += f0.x; a.v1 += f0.y; a.v2 += f1.x; a.v3 += f1.y;
    a.v4 += f2.x; a.v5 += f2.y; a.v6 += f3.x; a.v7 += f3.y;
}

// Shared gather over edge range [eBp[d], eEp[d]). SELFH=1: add self row when
// d in half0 (pass 0); SELFH=0: when d in half1 (pass 1) -- keeps every
// table access inside the pass's L2-resident half. srcsB holds byte offsets.
// Ghost lanes 60-63 shadow group 11 (results discarded via act).
#define GATHERG(tin, eBp, eEp, SELFH)                                          \
    int wv = (blockIdx.x * blockDim.x + threadIdx.x) >> 6;                     \
    int lane = threadIdx.x & 63;                                               \
    int g = lane / 5;                                                          \
    int sl = lane - g * 5;                                                     \
    if (g > 11) { g = 11; sl = 0; }                                            \
    int d = wv * 12 + g;                                                       \
    int act = (lane < 60) && (d < N);                                          \
    int dc = min(d, N - 1);                                                    \
    int e0 = (eBp)[dc];                                                        \
    int e1 = (eEp)[dc];                                                        \
    if (d >= N) e1 = e0;                                                       \
    int slo = sl << 4;                                                         \
    const char* tbs = (const char*)(tin) + slo;                                \
    F8 A = {0,0,0,0,0,0,0,0}, B = {0,0,0,0,0,0,0,0};                           \
    if ((SELFH) ? (dc < HALF_SPLIT) : (dc >= HALF_SPLIT)) {                    \
        uint4 rs = *reinterpret_cast<const uint4*>(tbs + (size_t)dc * 80);     \
        acc8(A, rs);                            /* self term row d */          \
    }                                                                          \
    int e = e0;                                                                \
    int ea = min(e1, (e0 + 3) & ~3);                                           \
    for (; e < ea; ++e) {                       /* align to 16 B */            \
        unsigned o = (unsigned)srcsB[e];                                       \
        uint4 r = *reinterpret_cast<const uint4*>(tbs + o);                    \
        acc8(A, r);                                                            \
    }                                                                          \
    for (; e + 4 <= e1; e += 4) {               /* 4 gathers in flight */      \
        int4 o4 = *reinterpret_cast<const int4*>(srcsB + e);                   \
        uint4 r0 = *reinterpret_cast<const uint4*>(tbs + (unsigned)o4.x);      \
        uint4 r1 = *reinterpret_cast<const uint4*>(tbs + (unsigned)o4.y);      \
        uint4 r2 = *reinterpret_cast<const uint4*>(tbs + (unsigned)o4.z);      \
        uint4 r3 = *reinterpret_cast<const uint4*>(tbs + (unsigned)o4.w);      \
        acc8(A, r0); acc8(B, r1); acc8(A, r2); acc8(B, r3);                    \
    }                                                                          \
    for (; e < e1; ++e) {                       /* tail <= 3 edges */          \
        unsigned o = (unsigned)srcsB[e];                                       \
        uint4 r = *reinterpret_cast<const uint4*>(tbs + o);                    \
        acc8(A, r);                                                            \
    }                                                                          \
    A.v0 += B.v0; A.v1 += B.v1; A.v2 += B.v2; A.v3 += B.v3;                    \
    A.v4 += B.v4; A.v5 += B.v5; A.v6 += B.v6; A.v7 += B.v7;

// Middle hop, pass 0 (src < HALF): tout[d] = raw f16 partial sums.
__global__ __launch_bounds__(256) void prop_hop0(
    const unsigned short* __restrict__ tin, unsigned short* __restrict__ tout,
    const int* __restrict__ starts, const int* __restrict__ mid,
    const int* __restrict__ srcsB, int N)
{
    GATHERG(tin, starts, mid, 1)
    if (act) {
        uint4 o;
        o.x = h2u(__floats2half2_rn(A.v0, A.v1));
        o.y = h2u(__floats2half2_rn(A.v2, A.v3));
        o.z = h2u(__floats2half2_rn(A.v4, A.v5));
        o.w = h2u(__floats2half2_rn(A.v6, A.v7));
        *reinterpret_cast<uint4*>((char*)tout + (size_t)d * 80 + slo) = o;
    }
}

// Middle hop, pass 1 (src >= HALF): tout[d] = f16( dd^2 * (partial + sum) ).
__global__ __launch_bounds__(256) void prop_hop1(
    const unsigned short* __restrict__ tin, unsigned short* __restrict__ tout,
    const int* __restrict__ starts, const int* __restrict__ mid,
    const int* __restrict__ srcsB, const float* __restrict__ dis, int N)
{
    GATHERG(tin, mid, starts + 1, 0)
    if (act) {
        uint4 pr = *reinterpret_cast<const uint4*>((const char*)tout + (size_t)d * 80 + slo);
        acc8(A, pr);
        float dd = dis[dc];
        float sc = dd * dd;
        uint4 o;
        o.x = h2u(__floats2half2_rn(sc * A.v0, sc * A.v1));
        o.y = h2u(__floats2half2_rn(sc * A.v2, sc * A.v3));
        o.z = h2u(__floats2half2_rn(sc * A.v4, sc * A.v5));
        o.w = h2u(__floats2half2_rn(sc * A.v6, sc * A.v7));
        *reinterpret_cast<uint4*>((char*)tout + (size_t)d * 80 + slo) = o;
    }
}

// Final hop, pass 0: out[d][*] = raw f32 partial (t[d] + sum over half0).
__global__ __launch_bounds__(256) void prop_fin0(
    const unsigned short* __restrict__ tin, float* __restrict__ out,
    const int* __restrict__ starts, const int* __restrict__ mid,
    const int* __restrict__ srcsB, int N)
{
    GATHERG(tin, starts, mid, 1)
    if (act) {
        float* ro = out + (size_t)d * N_CLASS + sl * 8;
        *reinterpret_cast<float4*>(ro)     = make_float4(A.v0, A.v1, A.v2, A.v3);
        *reinterpret_cast<float4*>(ro + 4) = make_float4(A.v4, A.v5, A.v6, A.v7);
    }
}

// Final hop, pass 1: sum over half1 + partial, bias + log_softmax.
// Softmax reduce = 4 rotate-shfls within the 5-lane group (12 nodes/wave).
__global__ __launch_bounds__(256) void prop_fin1(
    const unsigned short* __restrict__ tin, float* __restrict__ out,
    const int* __restrict__ starts, const int* __restrict__ mid,
    const int* __restrict__ srcsB, const float* __restrict__ dis,
    const float* __restrict__ bias, int N)
{
    GATHERG(tin, mid, starts + 1, 0)
    float dd = dis[dc];
    const float* pp = out + (size_t)dc * N_CLASS + sl * 8;
    float4 plo = *reinterpret_cast<const float4*>(pp);
    float4 phi = *reinterpret_cast<const float4*>(pp + 4);
    float4 blo = reinterpret_cast<const float4*>(bias)[sl * 2];       // sl<5
    float4 bhi = reinterpret_cast<const float4*>(bias)[sl * 2 + 1];
    float v0 = dd * (plo.x + A.v0) + blo.x, v1 = dd * (plo.y + A.v1) + blo.y;
    float v2 = dd * (plo.z + A.v2) + blo.z, v3 = dd * (plo.w + A.v3) + blo.w;
    float v4 = dd * (phi.x + A.v4) + bhi.x, v5 = dd * (phi.y + A.v5) + bhi.y;
    float v6 = dd * (phi.z + A.v6) + bhi.z, v7 = dd * (phi.w + A.v7) + bhi.w;
    float mx = fmaxf(fmaxf(fmaxf(v0, v1), fmaxf(v2, v3)),
                     fmaxf(fmaxf(v4, v5), fmaxf(v6, v7)));
    int rot = g * 5 + ((sl + 1 == 5) ? 0 : sl + 1);     // next lane in group
    float tmx = mx;
    #pragma unroll
    for (int k = 0; k < 4; ++k) { tmx = __shfl(tmx, rot); mx = fmaxf(mx, tmx); }
    float s = expf(v0 - mx) + expf(v1 - mx) + expf(v2 - mx) + expf(v3 - mx)
            + expf(v4 - mx) + expf(v5 - mx) + expf(v6 - mx) + expf(v7 - mx);
    float ts = s;
    #pragma unroll
    for (int k = 0; k < 4; ++k) { ts = __shfl(ts, rot); s += ts; }
    if (act) {
        float ls = mx + logf(s);
        float* ro = out + (size_t)d * N_CLASS + sl * 8;
        *reinterpret_cast<float4*>(ro)     = make_float4(v0 - ls, v1 - ls, v2 - ls, v3 - ls);
        *reinterpret_cast<float4*>(ro + 4) = make_float4(v4 - ls, v5 - ls, v6 - ls, v7 - ls);
    }
}

// ---------------------------------------------------------------------------
extern "C" void kernel_launch(void* const* d_in, const int* in_sizes, int n_in,
                              void* d_out, int out_size, void* d_ws, size_t ws_size,
                              hipStream_t stream) {
    const float* feature = (const float*)d_in[0];   // [N, 128]
    const float* weight  = (const float*)d_in[1];   // [40, 128]
    const float* bias    = (const float*)d_in[2];   // [40]
    const int*   ei      = (const int*)d_in[3];     // [2, E] (int32 or int64 words)
    const int N = N_NODES;
    const int E = in_sizes[3] / 2;

    size_t off = 0;
    auto take = [&](size_t bytes) { size_t o = off; off += (bytes + 255) & ~(size_t)255; return o; };
    char* ws = (char*)d_ws;
    int*   flag      = (int*)  (ws + take(4));
    int*   bCount    = (int*)  (ws + take((size_t)NBALLOC * 4));
    int*   bStart    = (int*)  (ws + take((size_t)(NBALLOC + 1) * 4));
    int*   bCursor   = (int*)  (ws + take((size_t)NBALLOC * 4));
    int*   coarseCnt = (int*)  (ws + take((size_t)NCALLOC * 4));
    int*   starts    = (int*)  (ws + take((size_t)(N + 1) * 4));
    int*   mid       = (int*)  (ws + take((size_t)N * 4));
    float* dis       = (float*)(ws + take((size_t)N * 4));
    // srcsB region also hosts tmpc (coarse records): tmpc dead before p4 writes srcsB
    size_t srcsBytes = (size_t)E * 4;
    size_t tmpcBytes = (size_t)NCALLOC * CCAP * 4;
    size_t bigBytes = srcsBytes > tmpcBytes ? srcsBytes : tmpcBytes;
    char* bigBase = ws + take(bigBytes);
    int* srcsB = (int*)bigBase;
    unsigned int* tmpc = (unsigned int*)bigBase;
    // t0+t1 (16 MB contiguous) also host tmp (fine records, E*4 = 12.8 MB)
    unsigned short* t0 = (unsigned short*)(ws + take((size_t)N * N_CLASS * 2));
    unsigned short* t1 = (unsigned short*)(ws + take((size_t)N * N_CLASS * 2));
    unsigned int* tmp = (unsigned int*)t0;

    // --- build CSR (two-level bucketed counting sort, pow2 ranges) ---
    detect_zero_kernel<<<1, 512, 0, stream>>>(ei, flag, bCount, coarseCnt);
    p3a_scatter<<<P3AGRID, 256, 0, stream>>>(ei, E, flag, bCount, coarseCnt, tmpc);
    p2_scan<<<1, NBALLOC, 0, stream>>>(bCount, bStart, bCursor, starts, E);
    p3b_scatter<<<NCUSED * 8, 256, 0, stream>>>(tmpc, coarseCnt, bCursor, tmp);
    p4_sort<<<NBUSED, 256, 0, stream>>>(tmp, bStart, starts, mid, dis, srcsB, N);

    // --- transform (MFMA, pre-scaled f16 rows) then 2 hops x 2 src-passes ---
    const int ntile = (N + 15) / 16;
    const int tblocks = (ntile * 64 + 255) / 256;
    transform_mfma<<<tblocks, 256, 0, stream>>>(feature, weight, dis, t0, N);
    const int nwaves = (N + 11) / 12;                     // 12 nodes per wave
    const int nodeBlocks = (nwaves * 64 + 255) / 256;
    prop_hop0<<<nodeBlocks, 256, 0, stream>>>(t0, t1, starts, mid, srcsB, N);
    prop_hop1<<<nodeBlocks, 256, 0, stream>>>(t0, t1, starts, mid, srcsB, dis, N);
    prop_fin0<<<nodeBlocks, 256, 0, stream>>>(t1, (float*)d_out, starts, mid, srcsB, N);
    prop_fin1<<<nodeBlocks, 256, 0, stream>>>(t1, (float*)d_out, starts, mid, srcsB,
                                              dis, bias, N);
}